// Round 11
// baseline (3364.016 us; speedup 1.0000x reference)
//
#include <hip/hip_runtime.h>

// ---------------------------------------------------------------------------
// MaskedTransformerEmbeddingCosine on MI355X (gfx950)
// R17: gemm_bt templated on SUBS (BK = SUBS*32). QKV keeps SUBS=2 (BK=64,
//      64 KB LDS — measured best at its 1920-block grid). Wo/W1/W2 move to
//      SUBS=1 (BK=32, 32 KB LDS) + __launch_bounds__(256,4): grids of
//      640/1280 blocks at 2 blocks/CU waste 17-25% in a partial last round;
//      4-5 blocks/CU makes Wo/W2 single-round and W1 1.25 rounds. SUBS=1
//      loop == verified R6 structure. attn keeps R13+R16 (Q-in-regs, T14
//      async V-stage); R12 de-split-K retained.
// ---------------------------------------------------------------------------

#define LSEQ   1024
#define DMODEL 640
#define NHEAD  10
#define DHEAD  64
#define NLAYER 6
#define BDIM   8
#define FDIM   1280
#define MROWS  (BDIM * LSEQ)

typedef __attribute__((ext_vector_type(8))) _Float16 half8;
typedef __attribute__((ext_vector_type(4))) _Float16 half4;
typedef __attribute__((ext_vector_type(2))) _Float16 half2v;
typedef __attribute__((ext_vector_type(4))) float    floatx4;
typedef __attribute__((ext_vector_type(2))) float    floatx2;

// ---------------------------------------------------------------------------
// C = A(M,:) @ B(N,:)^T + bias [+ res] [relu]; row stride ld.
// 128x128 tile, 4 waves each 64x64 (4x4 of 16x16x32), BK = SUBS*32.
// Register staging: iter i prefetches tile i+1 into VGPRs right after the
// barrier, computes from LDS, then ds_writes tile i+1.
// ---------------------------------------------------------------------------
template <bool RELU, bool RESADD, int SUBS>
__global__ __launch_bounds__(256, SUBS == 1 ? 4 : 2) void gemm_bt(
    const _Float16* __restrict__ A, const _Float16* __restrict__ Bw,
    const float* __restrict__ bias, const _Float16* __restrict__ res,
    _Float16* __restrict__ Cout, int M, int N, int K, int ld) {
  __shared__ _Float16 As[2][SUBS][128 * 32];
  __shared__ _Float16 Bs[2][SUBS][128 * 32];
  const int m0 = blockIdx.x * 128, n0 = blockIdx.y * 128;
  const int tid = threadIdx.x;
  const int w = tid >> 6, lane = tid & 63;
  const int quad = lane >> 4, l16 = lane & 15;
  const int wm = w >> 1, wn = w & 1;

  floatx4 acc[4][4];
#pragma unroll
  for (int i = 0; i < 4; i++)
#pragma unroll
    for (int j = 0; j < 4; j++) acc[i][j] = (floatx4){0.f, 0.f, 0.f, 0.f};

  // staging map: lane -> row w*16+(lane>>2); k-chunk xor-swizzled in the row
  const int arow = w * 16 + (lane >> 2);
  const int kswz = ((lane & 3) ^ ((lane >> 3) & 3)) * 8;
  const _Float16* ag = A + (size_t)(m0 + arow) * ld + kswz;
  const _Float16* bg = Bw + (size_t)(n0 + arow) * ld + kswz;
  const size_t r64 = (size_t)64 * ld;
  // LDS write slot (halves): slot lane&3 holds global chunk (lane&3)^((row>>1)&3)
  const int wofs0 = arow * 32 + (lane & 3) * 8;
  const int wofs1 = wofs0 + 64 * 32;

  // fragment-read: row l16, chunk quad lives at slot quad^((l16>>1)&3)
  const int fro = l16 * 32 + ((quad ^ ((l16 >> 1) & 3)) * 8);

  const int nIter = K / (SUBS * 32);
  {  // prologue: tile 0 -> regs -> buf 0
#pragma unroll
    for (int s = 0; s < SUBS; s++) {
      uint4 a0 = *(const uint4*)(ag + s * 32);
      uint4 a1 = *(const uint4*)(ag + s * 32 + r64);
      uint4 b0 = *(const uint4*)(bg + s * 32);
      uint4 b1 = *(const uint4*)(bg + s * 32 + r64);
      *(uint4*)&As[0][s][wofs0] = a0;
      *(uint4*)&As[0][s][wofs1] = a1;
      *(uint4*)&Bs[0][s][wofs0] = b0;
      *(uint4*)&Bs[0][s][wofs1] = b1;
    }
    ag += SUBS * 32; bg += SUBS * 32;
  }

  for (int i = 0; i < nIter; i++) {
    __syncthreads();
    uint4 aR[SUBS][2], bR[SUBS][2];
    const bool pf = (i + 1 < nIter);
    if (pf) {  // issue next tile's loads NOW; consumed after the MFMA phase
#pragma unroll
      for (int s = 0; s < SUBS; s++) {
        aR[s][0] = *(const uint4*)(ag + s * 32);
        aR[s][1] = *(const uint4*)(ag + s * 32 + r64);
        bR[s][0] = *(const uint4*)(bg + s * 32);
        bR[s][1] = *(const uint4*)(bg + s * 32 + r64);
      }
      ag += SUBS * 32; bg += SUBS * 32;
    }
#pragma unroll
    for (int sub = 0; sub < SUBS; sub++) {
      const _Float16* as = As[i & 1][sub];
      const _Float16* bs = Bs[i & 1][sub];
      half8 af[4], bf[4];
#pragma unroll
      for (int mt = 0; mt < 4; mt++)
        af[mt] = *(const half8*)&as[(wm * 64 + mt * 16) * 32 + fro];
#pragma unroll
      for (int nt = 0; nt < 4; nt++)
        bf[nt] = *(const half8*)&bs[(wn * 64 + nt * 16) * 32 + fro];
#pragma unroll
      for (int mt = 0; mt < 4; mt++)
#pragma unroll
        for (int nt = 0; nt < 4; nt++)
          acc[mt][nt] = __builtin_amdgcn_mfma_f32_16x16x32_f16(af[mt], bf[nt], acc[mt][nt], 0, 0, 0);
    }
    if (pf) {  // compiler inserts fine-grained vmcnt right before these
      const int nb = (i + 1) & 1;
#pragma unroll
      for (int s = 0; s < SUBS; s++) {
        *(uint4*)&As[nb][s][wofs0] = aR[s][0];
        *(uint4*)&As[nb][s][wofs1] = aR[s][1];
        *(uint4*)&Bs[nb][s][wofs0] = bR[s][0];
        *(uint4*)&Bs[nb][s][wofs1] = bR[s][1];
      }
    }
  }

  float bv[4];
#pragma unroll
  for (int nt = 0; nt < 4; nt++)
    bv[nt] = bias[n0 + wn * 64 + nt * 16 + l16];
#pragma unroll
  for (int mt = 0; mt < 4; mt++) {
#pragma unroll
    for (int reg = 0; reg < 4; reg++) {
      const int row = m0 + wm * 64 + mt * 16 + quad * 4 + reg;
#pragma unroll
      for (int nt = 0; nt < 4; nt++) {
        const int col = n0 + wn * 64 + nt * 16 + l16;
        float v = acc[mt][nt][reg] + bv[nt];
        if (RESADD) v += (float)res[(size_t)row * N + col];
        if (RELU) v = fmaxf(v, 0.f);
        Cout[(size_t)row * N + col] = (_Float16)v;
      }
    }
  }
}

// ---------------------------------------------------------------------------
// Banded attention: one block per (64-query tile, head, row-batch of 1024).
// T14 async-STAGE: V global loads issue in phase 0 (held in regs); the
// V->Vt LDS scatter runs AFTER QK^T. Q in regs (R13); Vt key-chunk XOR
// swizzle (R9). 3 barriers; LDS 53.2 KB -> 3 blocks/CU.
// ---------------------------------------------------------------------------
__global__ __launch_bounds__(256) void attn_kernel(const _Float16* __restrict__ qkv,
                                                   _Float16* __restrict__ o) {
  __shared__ _Float16 KP[192 * 72];   // K tiles; later reused as P (64 x 200)
  __shared__ _Float16 Vt[64 * 200];   // V transposed (key-swizzled)
  const int qb = blockIdx.x, h = blockIdx.y, b = blockIdx.z;
  const int q0 = qb * 64;
  const int kc0 = (q0 - 64 > 0) ? q0 - 64 : 0;
  const int kend = (q0 + 128 < LSEQ) ? q0 + 128 : LSEQ;
  const int cnt = kend - kc0;
  const int tid = threadIdx.x;
  const int w = tid >> 6, lane = tid & 63, quad = lane >> 4, l16 = lane & 15;

  // ---- phase 0: issue V loads into regs; stage K; load Q frags ----
  uint4 vreg[6];
#pragma unroll
  for (int it = 0; it < 6; it++) {
    const int c = tid + it * 256;
    const int row = c >> 3, ch = c & 7;
    uint4 v = {0u, 0u, 0u, 0u};
    if (row < cnt)
      v = *(const uint4*)(qkv + (size_t)(b * LSEQ + kc0 + row) * (3 * DMODEL) + 2 * DMODEL + h * DHEAD + ch * 8);
    vreg[it] = v;
  }
  half8 qf[2];
#pragma unroll
  for (int ks = 0; ks < 2; ks++)
    qf[ks] = *(const half8*)(qkv + (size_t)(b * LSEQ + q0 + w * 16 + l16) * (3 * DMODEL) +
                             h * DHEAD + ks * 32 + quad * 8);
#pragma unroll
  for (int it = 0; it < 6; it++) {
    const int c = tid + it * 256;
    const int row = c >> 3, ch = c & 7;
    uint4 v = {0u, 0u, 0u, 0u};
    if (row < cnt)
      v = *(const uint4*)(qkv + (size_t)(b * LSEQ + kc0 + row) * (3 * DMODEL) + DMODEL + h * DHEAD + ch * 8);
    *(uint4*)&KP[row * 72 + ch * 8] = v;
  }
  __syncthreads();  // (A) K staged; V loads still in flight

  // ---- QK^T (V latency hides under these MFMAs) ----
  floatx4 sacc[12];
#pragma unroll
  for (int i = 0; i < 12; i++) sacc[i] = (floatx4){0.f, 0.f, 0.f, 0.f};
#pragma unroll
  for (int ks = 0; ks < 2; ks++) {
#pragma unroll
    for (int nt = 0; nt < 12; nt++) {
      const half8 kf = *(const half8*)&KP[(nt * 16 + l16) * 72 + ks * 32 + quad * 8];
      sacc[nt] = __builtin_amdgcn_mfma_f32_16x16x32_f16(qf[ks], kf, sacc[nt], 0, 0, 0);
    }
  }

  // ---- write Vt from regs (disjoint from KP; lands before barrier C) ----
#pragma unroll
  for (int it = 0; it < 6; it++) {
    const int c = tid + it * 256;
    const int row = c >> 3, ch = c & 7;
    _Float16 tmp[8];
    *(uint4*)tmp = vreg[it];
    const int rs = row ^ (ch << 3);  // key-swizzle by d>>3 (= ch), bijective in [0,192)
#pragma unroll
    for (int jj = 0; jj < 8; jj++) Vt[(ch * 8 + jj) * 200 + rs] = tmp[jj];
  }
  __syncthreads();  // (B) all K reads done; Vt writes done

  // ---- softmax; P overwrites K region of KP ----
#pragma unroll
  for (int r = 0; r < 4; r++) {
    const int qi = q0 + w * 16 + quad * 4 + r;
    float sv[12];
    float m = -1e30f;
#pragma unroll
    for (int nt = 0; nt < 12; nt++) {
      const int key = kc0 + nt * 16 + l16;
      const bool ok = (key >= qi - 64) && (key <= qi + 64) && (key < LSEQ);
      const float s = ok ? sacc[nt][r] * 0.125f : -1e30f;
      sv[nt] = s;
      m = fmaxf(m, s);
    }
#pragma unroll
    for (int d = 1; d < 16; d <<= 1) m = fmaxf(m, __shfl_xor(m, d));
    float sum = 0.f;
#pragma unroll
    for (int nt = 0; nt < 12; nt++) {
      const float p = __expf(sv[nt] - m);
      sv[nt] = p;
      sum += p;
    }
#pragma unroll
    for (int d = 1; d < 16; d <<= 1) sum += __shfl_xor(sum, d);
    const float inv = 1.f / sum;
    _Float16* Pr = &KP[(w * 16 + quad * 4 + r) * 200];
#pragma unroll
    for (int nt = 0; nt < 12; nt++) Pr[nt * 16 + l16] = (_Float16)(sv[nt] * inv);
  }
  __syncthreads();  // (C)

  // ---- PV ----
  floatx4 oacc[4];
#pragma unroll
  for (int i = 0; i < 4; i++) oacc[i] = (floatx4){0.f, 0.f, 0.f, 0.f};
#pragma unroll
  for (int ks = 0; ks < 6; ks++) {
    const half8 pf = *(const half8*)&KP[(w * 16 + l16) * 200 + ks * 32 + quad * 8];
#pragma unroll
    for (int nt = 0; nt < 4; nt++) {
      const int dsw = ((nt * 2 + (l16 >> 3)) & 7) << 3;  // (d>>3)&7 of this lane's V row
      const half8 vf = *(const half8*)&Vt[(nt * 16 + l16) * 200 + ((ks * 32 + quad * 8) ^ dsw)];
      oacc[nt] = __builtin_amdgcn_mfma_f32_16x16x32_f16(pf, vf, oacc[nt], 0, 0, 0);
    }
  }
#pragma unroll
  for (int nt = 0; nt < 4; nt++)
#pragma unroll
    for (int reg = 0; reg < 4; reg++) {
      const int row = q0 + w * 16 + quad * 4 + reg;
      const int col = h * DHEAD + nt * 16 + l16;
      o[(size_t)(b * LSEQ + row) * DMODEL + col] = (_Float16)oacc[nt][reg];
    }
}

// ---------------------------------------------------------------------------
// h = LayerNorm(s) — fp16 in (bias+residual already applied), fp16 out.
// One wave/row, vectorized 640 = 64*4 + 64*4 + 64*2.
// ---------------------------------------------------------------------------
__global__ __launch_bounds__(256) void ln_res1_kernel(const _Float16* __restrict__ s0,
                                                      const float* __restrict__ g,
                                                      const float* __restrict__ bta,
                                                      _Float16* __restrict__ hh) {
  const int row = blockIdx.x * 4 + (threadIdx.x >> 6);
  const int lane = threadIdx.x & 63;
  const _Float16* p0 = s0 + (size_t)row * DMODEL;
  const half4  a0 = *(const half4*)(p0 + lane * 4);
  const half4  a1 = *(const half4*)(p0 + 256 + lane * 4);
  const half2v a2 = *(const half2v*)(p0 + 512 + lane * 2);
  float v[10], s = 0.f, ss = 0.f;
#pragma unroll
  for (int j = 0; j < 4; j++) v[j] = (float)a0[j];
#pragma unroll
  for (int j = 0; j < 4; j++) v[4 + j] = (float)a1[j];
#pragma unroll
  for (int j = 0; j < 2; j++) v[8 + j] = (float)a2[j];
#pragma unroll
  for (int i = 0; i < 10; i++) { s += v[i]; ss += v[i] * v[i]; }
#pragma unroll
  for (int d = 1; d < 64; d <<= 1) { s += __shfl_xor(s, d); ss += __shfl_xor(ss, d); }
  const float mean = s * (1.f / DMODEL);
  const float var = ss * (1.f / DMODEL) - mean * mean;
  const float rstd = rsqrtf(var + 1e-5f);
  const floatx4 g0 = *(const floatx4*)(g + lane * 4);
  const floatx4 g1 = *(const floatx4*)(g + 256 + lane * 4);
  const floatx2 g2 = *(const floatx2*)(g + 512 + lane * 2);
  const floatx4 b0 = *(const floatx4*)(bta + lane * 4);
  const floatx4 b1 = *(const floatx4*)(bta + 256 + lane * 4);
  const floatx2 b2 = *(const floatx2*)(bta + 512 + lane * 2);
  _Float16* outp = hh + (size_t)row * DMODEL;
  half4 o0, o1;
  half2v o2;
#pragma unroll
  for (int j = 0; j < 4; j++) o0[j] = (_Float16)((v[j] - mean) * rstd * g0[j] + b0[j]);
#pragma unroll
  for (int j = 0; j < 4; j++) o1[j] = (_Float16)((v[4 + j] - mean) * rstd * g1[j] + b1[j]);
#pragma unroll
  for (int j = 0; j < 2; j++) o2[j] = (_Float16)((v[8 + j] - mean) * rstd * g2[j] + b2[j]);
  *(half4*)(outp + lane * 4) = o0;
  *(half4*)(outp + 256 + lane * 4) = o1;
  *(half2v*)(outp + 512 + lane * 2) = o2;
}

__global__ void cvt_kernel(const float* __restrict__ s, _Float16* __restrict__ d, int n) {
  int i = blockIdx.x * blockDim.x + threadIdx.x;
  const int stride = gridDim.x * blockDim.x;
  for (; i < n; i += stride) d[i] = (_Float16)s[i];
}

__global__ void zero_kernel(float* __restrict__ p, int n) {
  const int i = blockIdx.x * blockDim.x + threadIdx.x;
  if (i < n) p[i] = 0.f;
}

__global__ void pool_kernel(const _Float16* __restrict__ h, float* __restrict__ pooled) {
  const int b = blockIdx.x, chunk = blockIdx.y;  // 32 rows per chunk
  for (int d = threadIdx.x; d < DMODEL; d += 256) {
    float s = 0.f;
    const _Float16* p = h + ((size_t)b * LSEQ + chunk * 32) * DMODEL + d;
#pragma unroll 4
    for (int l = 0; l < 32; l++) s += (float)p[(size_t)l * DMODEL];
    atomicAdd(&pooled[b * DMODEL + d], s);
  }
}

__global__ void lnvec_kernel(const float* __restrict__ pooled, const float* __restrict__ g,
                             const float* __restrict__ bta, float* __restrict__ eln) {
  const int b = blockIdx.x, lane = threadIdx.x;  // 64 threads
  float v[10], s = 0.f, ss = 0.f;
#pragma unroll
  for (int i = 0; i < 10; i++) {
    const float x = pooled[b * DMODEL + lane + 64 * i];
    v[i] = x; s += x; ss += x * x;
  }
#pragma unroll
  for (int d = 1; d < 64; d <<= 1) { s += __shfl_xor(s, d); ss += __shfl_xor(ss, d); }
  const float mean = s * (1.f / DMODEL);
  const float var = ss * (1.f / DMODEL) - mean * mean;
  const float rstd = rsqrtf(var + 1e-5f);
#pragma unroll
  for (int i = 0; i < 10; i++) {
    const int d = lane + 64 * i;
    eln[b * DMODEL + d] = (v[i] - mean) * rstd * g[d] + bta[d];
  }
}

// one wave per output element
__global__ __launch_bounds__(256) void embed_kernel(const float* __restrict__ eln,
                                                    const float* __restrict__ We,
                                                    const float* __restrict__ be,
                                                    float* __restrict__ e) {
  const int gw = (blockIdx.x << 2) + (threadIdx.x >> 6);
  const int lane = threadIdx.x & 63;
  const int b = gw / DMODEL, n = gw % DMODEL;
  const float* wr = We + (size_t)n * DMODEL;
  const float* er = eln + (size_t)b * DMODEL;
  float s = 0.f;
#pragma unroll
  for (int i = 0; i < 10; i++) s += wr[lane + 64 * i] * er[lane + 64 * i];
#pragma unroll
  for (int d = 1; d < 64; d <<= 1) s += __shfl_xor(s, d);
  if (lane == 0) e[(size_t)b * DMODEL + n] = fmaxf(s + be[n], 0.f);
}

__global__ void cosine_kernel(const float* __restrict__ ex, const float* __restrict__ ey,
                              float* __restrict__ out) {
  const int b = blockIdx.x, lane = threadIdx.x;  // 64 threads
  float sxy = 0.f, sxx = 0.f, syy = 0.f;
#pragma unroll
  for (int i = 0; i < 10; i++) {
    const float x = ex[b * DMODEL + lane + 64 * i];
    const float y = ey[b * DMODEL + lane + 64 * i];
    sxy += x * y; sxx += x * x; syy += y * y;
  }
#pragma unroll
  for (int d = 1; d < 64; d <<= 1) {
    sxy += __shfl_xor(sxy, d); sxx += __shfl_xor(sxx, d); syy += __shfl_xor(syy, d);
  }
  if (lane == 0) {
    const float nx = fmaxf(sqrtf(sxx), 1e-8f);
    const float ny = fmaxf(sqrtf(syy), 1e-8f);
    out[b] = sxy / (nx * ny);
  }
}

// ---------------------------------------------------------------------------

extern "C" void kernel_launch(void* const* d_in, const int* in_sizes, int n_in,
                              void* d_out, int out_size, void* d_ws, size_t ws_size,
                              hipStream_t stream) {
  (void)in_sizes; (void)n_in; (void)out_size;
  const float* x    = (const float*)d_in[0];
  const float* y    = (const float*)d_in[3];
  const float* Wqkv = (const float*)d_in[6];
  const float* bqkv = (const float*)d_in[7];
  const float* Wo   = (const float*)d_in[8];
  const float* bo   = (const float*)d_in[9];
  const float* ln1g = (const float*)d_in[10];
  const float* ln1b = (const float*)d_in[11];
  const float* W1   = (const float*)d_in[12];
  const float* b1   = (const float*)d_in[13];
  const float* W2   = (const float*)d_in[14];
  const float* b2   = (const float*)d_in[15];
  const float* ln2g = (const float*)d_in[16];
  const float* ln2b = (const float*)d_in[17];
  const float* lneg = (const float*)d_in[18];
  const float* lneb = (const float*)d_in[19];
  const float* We   = (const float*)d_in[20];
  const float* be   = (const float*)d_in[21];

  auto algn = [](size_t b) { return (b + 255) & ~(size_t)255; };
  const size_t wbytes = algn((size_t)NLAYER * 3 * DMODEL * DMODEL * 2) +
                        algn((size_t)NLAYER * DMODEL * DMODEL * 2) +
                        2 * algn((size_t)NLAYER * FDIM * DMODEL * 2);
  auto actbytes = [&](size_t R) {
    return algn(R * DMODEL * 2) + algn(R * 3 * DMODEL * 2) + algn(R * FDIM * 2) +
           4 * algn((size_t)BDIM * DMODEL * 4);
  };
  const int NS = (wbytes + actbytes((size_t)2 * MROWS) <= ws_size) ? 2 : 1;
  const size_t R = (size_t)NS * MROWS;

  char* ws = (char*)d_ws;
  size_t off = 0;
  auto alloc = [&](size_t bytes) -> char* {
    char* p = ws + off;
    off += algn(bytes);
    return p;
  };
  _Float16* Wqkv_h = (_Float16*)alloc((size_t)NLAYER * 3 * DMODEL * DMODEL * 2);
  _Float16* Wo_h   = (_Float16*)alloc((size_t)NLAYER * DMODEL * DMODEL * 2);
  _Float16* W1_h   = (_Float16*)alloc((size_t)NLAYER * FDIM * DMODEL * 2);
  _Float16* W2_h   = (_Float16*)alloc((size_t)NLAYER * DMODEL * FDIM * 2);
  _Float16* h_h    = (_Float16*)alloc(R * DMODEL * 2);
  _Float16* qkv_h  = (_Float16*)alloc(R * 3 * DMODEL * 2);  // aliases tmp
  _Float16* ff_h   = (_Float16*)alloc(R * FDIM * 2);        // aliases o_h
  float*    pooled = (float*)   alloc((size_t)BDIM * DMODEL * 4);
  float*    elnb   = (float*)   alloc((size_t)BDIM * DMODEL * 4);
  float*    exb    = (float*)   alloc((size_t)BDIM * DMODEL * 4);
  float*    eyb    = (float*)   alloc((size_t)BDIM * DMODEL * 4);
  if (off > ws_size) return;
  _Float16* tmp  = qkv_h;    // pre-LN sums; qkv dead once attn has run
  _Float16* o_h  = ff_h;     // o dead before ff is written

  cvt_kernel<<<2048, 256, 0, stream>>>(Wqkv, Wqkv_h, NLAYER * 3 * DMODEL * DMODEL);
  cvt_kernel<<<2048, 256, 0, stream>>>(Wo,   Wo_h,   NLAYER * DMODEL * DMODEL);
  cvt_kernel<<<2048, 256, 0, stream>>>(W1,   W1_h,   NLAYER * FDIM * DMODEL);
  cvt_kernel<<<2048, 256, 0, stream>>>(W2,   W2_h,   NLAYER * DMODEL * FDIM);

  const float* seq_in[2] = {x, y};
  float* eouts[2] = {exb, eyb};
  const int Mr = (int)R;

  for (int s0 = 0; s0 < 2; s0 += NS) {
    for (int s = 0; s < NS; s++)
      cvt_kernel<<<2048, 256, 0, stream>>>(
          seq_in[s0 + s], h_h + (size_t)s * MROWS * DMODEL, MROWS * DMODEL);
    for (int l = 0; l < NLAYER; l++) {
      // qkv = h @ Wqkv^T + bqkv
      gemm_bt<false, false, 2><<<dim3(Mr / 128, 15), 256, 0, stream>>>(
          h_h, Wqkv_h + (size_t)l * 3 * DMODEL * DMODEL, bqkv + l * 3 * DMODEL,
          nullptr, qkv_h, Mr, 3 * DMODEL, DMODEL, DMODEL);
      attn_kernel<<<dim3(LSEQ / 64, NHEAD, Mr / LSEQ), 256, 0, stream>>>(qkv_h, o_h);
      // tmp = o @ Wo^T + bo + h   (full K, residual inline)
      gemm_bt<false, true, 1><<<dim3(Mr / 128, 5), 256, 0, stream>>>(
          o_h, Wo_h + (size_t)l * DMODEL * DMODEL, bo + l * DMODEL,
          h_h, tmp, Mr, DMODEL, DMODEL, DMODEL);
      ln_res1_kernel<<<Mr / 4, 256, 0, stream>>>(
          tmp, ln1g + l * DMODEL, ln1b + l * DMODEL, h_h);
      // ff = relu(h @ W1^T + b1)
      gemm_bt<true, false, 1><<<dim3(Mr / 128, 10), 256, 0, stream>>>(
          h_h, W1_h + (size_t)l * FDIM * DMODEL, b1 + l * FDIM,
          nullptr, ff_h, Mr, FDIM, DMODEL, DMODEL);
      // tmp = ff @ W2^T + b2 + h  (full K=1280, residual inline)
      gemm_bt<false, true, 1><<<dim3(Mr / 128, 5), 256, 0, stream>>>(
          ff_h, W2_h + (size_t)l * DMODEL * FDIM, b2 + l * DMODEL,
          h_h, tmp, Mr, DMODEL, FDIM, FDIM);
      ln_res1_kernel<<<Mr / 4, 256, 0, stream>>>(
          tmp, ln2g + l * DMODEL, ln2b + l * DMODEL, h_h);
    }
    for (int s = 0; s < NS; s++) {
      const _Float16* hseq = h_h + (size_t)s * MROWS * DMODEL;
      zero_kernel<<<(BDIM * DMODEL + 255) / 256, 256, 0, stream>>>(pooled, BDIM * DMODEL);
      pool_kernel<<<dim3(BDIM, 32), 256, 0, stream>>>(hseq, pooled);
      lnvec_kernel<<<BDIM, 64, 0, stream>>>(pooled, lneg, lneb, elnb);
      embed_kernel<<<BDIM * DMODEL / 4, 256, 0, stream>>>(elnb, We, be, eouts[s0 + s]);
    }
  }
  cosine_kernel<<<BDIM, 64, 0, stream>>>(exb, eyb, (float*)d_out);
}

// Round 12
// 3359.041 us; speedup vs baseline: 1.0015x; 1.0015x over previous
//
#include <hip/hip_runtime.h>

// ---------------------------------------------------------------------------
// MaskedTransformerEmbeddingCosine on MI355X (gfx950)
// R18: R17's SUBS=1 retry WITHOUT the launch_bounds clamp. R17's
//      __launch_bounds__(256,4) forced VGPR 52 < the ~90-reg working set ->
//      accumulator spills (WRITE_SIZE 155MB vs 21MB real output, MfmaUtil 7%,
//      149 µs/GEMM). Default bounds restore natural ~80-VGPR allocation;
//      32 KB LDS then lifts Wo/W1/W2 residency to 4-5 blocks/CU organically
//      (grid-tail theory: 640/1280-block grids at 2 blocks/CU waste 17-25%).
//      QKV stays SUBS=2 (measured best). attn keeps R13+R16; R12 de-split-K.
// ---------------------------------------------------------------------------

#define LSEQ   1024
#define DMODEL 640
#define NHEAD  10
#define DHEAD  64
#define NLAYER 6
#define BDIM   8
#define FDIM   1280
#define MROWS  (BDIM * LSEQ)

typedef __attribute__((ext_vector_type(8))) _Float16 half8;
typedef __attribute__((ext_vector_type(4))) _Float16 half4;
typedef __attribute__((ext_vector_type(2))) _Float16 half2v;
typedef __attribute__((ext_vector_type(4))) float    floatx4;
typedef __attribute__((ext_vector_type(2))) float    floatx2;

// ---------------------------------------------------------------------------
// C = A(M,:) @ B(N,:)^T + bias [+ res] [relu]; row stride ld.
// 128x128 tile, 4 waves each 64x64 (4x4 of 16x16x32), BK = SUBS*32.
// Register staging: iter i prefetches tile i+1 into VGPRs right after the
// barrier, computes from LDS, then ds_writes tile i+1.
// ---------------------------------------------------------------------------
template <bool RELU, bool RESADD, int SUBS>
__global__ __launch_bounds__(256) void gemm_bt(
    const _Float16* __restrict__ A, const _Float16* __restrict__ Bw,
    const float* __restrict__ bias, const _Float16* __restrict__ res,
    _Float16* __restrict__ Cout, int M, int N, int K, int ld) {
  __shared__ _Float16 As[2][SUBS][128 * 32];
  __shared__ _Float16 Bs[2][SUBS][128 * 32];
  const int m0 = blockIdx.x * 128, n0 = blockIdx.y * 128;
  const int tid = threadIdx.x;
  const int w = tid >> 6, lane = tid & 63;
  const int quad = lane >> 4, l16 = lane & 15;
  const int wm = w >> 1, wn = w & 1;

  floatx4 acc[4][4];
#pragma unroll
  for (int i = 0; i < 4; i++)
#pragma unroll
    for (int j = 0; j < 4; j++) acc[i][j] = (floatx4){0.f, 0.f, 0.f, 0.f};

  // staging map: lane -> row w*16+(lane>>2); k-chunk xor-swizzled in the row
  const int arow = w * 16 + (lane >> 2);
  const int kswz = ((lane & 3) ^ ((lane >> 3) & 3)) * 8;
  const _Float16* ag = A + (size_t)(m0 + arow) * ld + kswz;
  const _Float16* bg = Bw + (size_t)(n0 + arow) * ld + kswz;
  const size_t r64 = (size_t)64 * ld;
  // LDS write slot (halves): slot lane&3 holds global chunk (lane&3)^((row>>1)&3)
  const int wofs0 = arow * 32 + (lane & 3) * 8;
  const int wofs1 = wofs0 + 64 * 32;

  // fragment-read: row l16, chunk quad lives at slot quad^((l16>>1)&3)
  const int fro = l16 * 32 + ((quad ^ ((l16 >> 1) & 3)) * 8);

  const int nIter = K / (SUBS * 32);
  {  // prologue: tile 0 -> regs -> buf 0
#pragma unroll
    for (int s = 0; s < SUBS; s++) {
      uint4 a0 = *(const uint4*)(ag + s * 32);
      uint4 a1 = *(const uint4*)(ag + s * 32 + r64);
      uint4 b0 = *(const uint4*)(bg + s * 32);
      uint4 b1 = *(const uint4*)(bg + s * 32 + r64);
      *(uint4*)&As[0][s][wofs0] = a0;
      *(uint4*)&As[0][s][wofs1] = a1;
      *(uint4*)&Bs[0][s][wofs0] = b0;
      *(uint4*)&Bs[0][s][wofs1] = b1;
    }
    ag += SUBS * 32; bg += SUBS * 32;
  }

  for (int i = 0; i < nIter; i++) {
    __syncthreads();
    uint4 aR[SUBS][2], bR[SUBS][2];
    const bool pf = (i + 1 < nIter);
    if (pf) {  // issue next tile's loads NOW; consumed after the MFMA phase
#pragma unroll
      for (int s = 0; s < SUBS; s++) {
        aR[s][0] = *(const uint4*)(ag + s * 32);
        aR[s][1] = *(const uint4*)(ag + s * 32 + r64);
        bR[s][0] = *(const uint4*)(bg + s * 32);
        bR[s][1] = *(const uint4*)(bg + s * 32 + r64);
      }
      ag += SUBS * 32; bg += SUBS * 32;
    }
#pragma unroll
    for (int sub = 0; sub < SUBS; sub++) {
      const _Float16* as = As[i & 1][sub];
      const _Float16* bs = Bs[i & 1][sub];
      half8 af[4], bf[4];
#pragma unroll
      for (int mt = 0; mt < 4; mt++)
        af[mt] = *(const half8*)&as[(wm * 64 + mt * 16) * 32 + fro];
#pragma unroll
      for (int nt = 0; nt < 4; nt++)
        bf[nt] = *(const half8*)&bs[(wn * 64 + nt * 16) * 32 + fro];
#pragma unroll
      for (int mt = 0; mt < 4; mt++)
#pragma unroll
        for (int nt = 0; nt < 4; nt++)
          acc[mt][nt] = __builtin_amdgcn_mfma_f32_16x16x32_f16(af[mt], bf[nt], acc[mt][nt], 0, 0, 0);
    }
    if (pf) {  // compiler inserts fine-grained vmcnt right before these
      const int nb = (i + 1) & 1;
#pragma unroll
      for (int s = 0; s < SUBS; s++) {
        *(uint4*)&As[nb][s][wofs0] = aR[s][0];
        *(uint4*)&As[nb][s][wofs1] = aR[s][1];
        *(uint4*)&Bs[nb][s][wofs0] = bR[s][0];
        *(uint4*)&Bs[nb][s][wofs1] = bR[s][1];
      }
    }
  }

  float bv[4];
#pragma unroll
  for (int nt = 0; nt < 4; nt++)
    bv[nt] = bias[n0 + wn * 64 + nt * 16 + l16];
#pragma unroll
  for (int mt = 0; mt < 4; mt++) {
#pragma unroll
    for (int reg = 0; reg < 4; reg++) {
      const int row = m0 + wm * 64 + mt * 16 + quad * 4 + reg;
#pragma unroll
      for (int nt = 0; nt < 4; nt++) {
        const int col = n0 + wn * 64 + nt * 16 + l16;
        float v = acc[mt][nt][reg] + bv[nt];
        if (RESADD) v += (float)res[(size_t)row * N + col];
        if (RELU) v = fmaxf(v, 0.f);
        Cout[(size_t)row * N + col] = (_Float16)v;
      }
    }
  }
}

// ---------------------------------------------------------------------------
// Banded attention: one block per (64-query tile, head, row-batch of 1024).
// T14 async-STAGE: V global loads issue in phase 0 (held in regs); the
// V->Vt LDS scatter runs AFTER QK^T. Q in regs (R13); Vt key-chunk XOR
// swizzle (R9). 3 barriers; LDS 53.2 KB -> 3 blocks/CU.
// ---------------------------------------------------------------------------
__global__ __launch_bounds__(256) void attn_kernel(const _Float16* __restrict__ qkv,
                                                   _Float16* __restrict__ o) {
  __shared__ _Float16 KP[192 * 72];   // K tiles; later reused as P (64 x 200)
  __shared__ _Float16 Vt[64 * 200];   // V transposed (key-swizzled)
  const int qb = blockIdx.x, h = blockIdx.y, b = blockIdx.z;
  const int q0 = qb * 64;
  const int kc0 = (q0 - 64 > 0) ? q0 - 64 : 0;
  const int kend = (q0 + 128 < LSEQ) ? q0 + 128 : LSEQ;
  const int cnt = kend - kc0;
  const int tid = threadIdx.x;
  const int w = tid >> 6, lane = tid & 63, quad = lane >> 4, l16 = lane & 15;

  // ---- phase 0: issue V loads into regs; stage K; load Q frags ----
  uint4 vreg[6];
#pragma unroll
  for (int it = 0; it < 6; it++) {
    const int c = tid + it * 256;
    const int row = c >> 3, ch = c & 7;
    uint4 v = {0u, 0u, 0u, 0u};
    if (row < cnt)
      v = *(const uint4*)(qkv + (size_t)(b * LSEQ + kc0 + row) * (3 * DMODEL) + 2 * DMODEL + h * DHEAD + ch * 8);
    vreg[it] = v;
  }
  half8 qf[2];
#pragma unroll
  for (int ks = 0; ks < 2; ks++)
    qf[ks] = *(const half8*)(qkv + (size_t)(b * LSEQ + q0 + w * 16 + l16) * (3 * DMODEL) +
                             h * DHEAD + ks * 32 + quad * 8);
#pragma unroll
  for (int it = 0; it < 6; it++) {
    const int c = tid + it * 256;
    const int row = c >> 3, ch = c & 7;
    uint4 v = {0u, 0u, 0u, 0u};
    if (row < cnt)
      v = *(const uint4*)(qkv + (size_t)(b * LSEQ + kc0 + row) * (3 * DMODEL) + DMODEL + h * DHEAD + ch * 8);
    *(uint4*)&KP[row * 72 + ch * 8] = v;
  }
  __syncthreads();  // (A) K staged; V loads still in flight

  // ---- QK^T (V latency hides under these MFMAs) ----
  floatx4 sacc[12];
#pragma unroll
  for (int i = 0; i < 12; i++) sacc[i] = (floatx4){0.f, 0.f, 0.f, 0.f};
#pragma unroll
  for (int ks = 0; ks < 2; ks++) {
#pragma unroll
    for (int nt = 0; nt < 12; nt++) {
      const half8 kf = *(const half8*)&KP[(nt * 16 + l16) * 72 + ks * 32 + quad * 8];
      sacc[nt] = __builtin_amdgcn_mfma_f32_16x16x32_f16(qf[ks], kf, sacc[nt], 0, 0, 0);
    }
  }

  // ---- write Vt from regs (disjoint from KP; lands before barrier C) ----
#pragma unroll
  for (int it = 0; it < 6; it++) {
    const int c = tid + it * 256;
    const int row = c >> 3, ch = c & 7;
    _Float16 tmp[8];
    *(uint4*)tmp = vreg[it];
    const int rs = row ^ (ch << 3);  // key-swizzle by d>>3 (= ch), bijective in [0,192)
#pragma unroll
    for (int jj = 0; jj < 8; jj++) Vt[(ch * 8 + jj) * 200 + rs] = tmp[jj];
  }
  __syncthreads();  // (B) all K reads done; Vt writes done

  // ---- softmax; P overwrites K region of KP ----
#pragma unroll
  for (int r = 0; r < 4; r++) {
    const int qi = q0 + w * 16 + quad * 4 + r;
    float sv[12];
    float m = -1e30f;
#pragma unroll
    for (int nt = 0; nt < 12; nt++) {
      const int key = kc0 + nt * 16 + l16;
      const bool ok = (key >= qi - 64) && (key <= qi + 64) && (key < LSEQ);
      const float s = ok ? sacc[nt][r] * 0.125f : -1e30f;
      sv[nt] = s;
      m = fmaxf(m, s);
    }
#pragma unroll
    for (int d = 1; d < 16; d <<= 1) m = fmaxf(m, __shfl_xor(m, d));
    float sum = 0.f;
#pragma unroll
    for (int nt = 0; nt < 12; nt++) {
      const float p = __expf(sv[nt] - m);
      sv[nt] = p;
      sum += p;
    }
#pragma unroll
    for (int d = 1; d < 16; d <<= 1) sum += __shfl_xor(sum, d);
    const float inv = 1.f / sum;
    _Float16* Pr = &KP[(w * 16 + quad * 4 + r) * 200];
#pragma unroll
    for (int nt = 0; nt < 12; nt++) Pr[nt * 16 + l16] = (_Float16)(sv[nt] * inv);
  }
  __syncthreads();  // (C)

  // ---- PV ----
  floatx4 oacc[4];
#pragma unroll
  for (int i = 0; i < 4; i++) oacc[i] = (floatx4){0.f, 0.f, 0.f, 0.f};
#pragma unroll
  for (int ks = 0; ks < 6; ks++) {
    const half8 pf = *(const half8*)&KP[(w * 16 + l16) * 200 + ks * 32 + quad * 8];
#pragma unroll
    for (int nt = 0; nt < 4; nt++) {
      const int dsw = ((nt * 2 + (l16 >> 3)) & 7) << 3;  // (d>>3)&7 of this lane's V row
      const half8 vf = *(const half8*)&Vt[(nt * 16 + l16) * 200 + ((ks * 32 + quad * 8) ^ dsw)];
      oacc[nt] = __builtin_amdgcn_mfma_f32_16x16x32_f16(pf, vf, oacc[nt], 0, 0, 0);
    }
  }
#pragma unroll
  for (int nt = 0; nt < 4; nt++)
#pragma unroll
    for (int reg = 0; reg < 4; reg++) {
      const int row = q0 + w * 16 + quad * 4 + reg;
      const int col = h * DHEAD + nt * 16 + l16;
      o[(size_t)(b * LSEQ + row) * DMODEL + col] = (_Float16)oacc[nt][reg];
    }
}

// ---------------------------------------------------------------------------
// h = LayerNorm(s) — fp16 in (bias+residual already applied), fp16 out.
// One wave/row, vectorized 640 = 64*4 + 64*4 + 64*2.
// ---------------------------------------------------------------------------
__global__ __launch_bounds__(256) void ln_res1_kernel(const _Float16* __restrict__ s0,
                                                      const float* __restrict__ g,
                                                      const float* __restrict__ bta,
                                                      _Float16* __restrict__ hh) {
  const int row = blockIdx.x * 4 + (threadIdx.x >> 6);
  const int lane = threadIdx.x & 63;
  const _Float16* p0 = s0 + (size_t)row * DMODEL;
  const half4  a0 = *(const half4*)(p0 + lane * 4);
  const half4  a1 = *(const half4*)(p0 + 256 + lane * 4);
  const half2v a2 = *(const half2v*)(p0 + 512 + lane * 2);
  float v[10], s = 0.f, ss = 0.f;
#pragma unroll
  for (int j = 0; j < 4; j++) v[j] = (float)a0[j];
#pragma unroll
  for (int j = 0; j < 4; j++) v[4 + j] = (float)a1[j];
#pragma unroll
  for (int j = 0; j < 2; j++) v[8 + j] = (float)a2[j];
#pragma unroll
  for (int i = 0; i < 10; i++) { s += v[i]; ss += v[i] * v[i]; }
#pragma unroll
  for (int d = 1; d < 64; d <<= 1) { s += __shfl_xor(s, d); ss += __shfl_xor(ss, d); }
  const float mean = s * (1.f / DMODEL);
  const float var = ss * (1.f / DMODEL) - mean * mean;
  const float rstd = rsqrtf(var + 1e-5f);
  const floatx4 g0 = *(const floatx4*)(g + lane * 4);
  const floatx4 g1 = *(const floatx4*)(g + 256 + lane * 4);
  const floatx2 g2 = *(const floatx2*)(g + 512 + lane * 2);
  const floatx4 b0 = *(const floatx4*)(bta + lane * 4);
  const floatx4 b1 = *(const floatx4*)(bta + 256 + lane * 4);
  const floatx2 b2 = *(const floatx2*)(bta + 512 + lane * 2);
  _Float16* outp = hh + (size_t)row * DMODEL;
  half4 o0, o1;
  half2v o2;
#pragma unroll
  for (int j = 0; j < 4; j++) o0[j] = (_Float16)((v[j] - mean) * rstd * g0[j] + b0[j]);
#pragma unroll
  for (int j = 0; j < 4; j++) o1[j] = (_Float16)((v[4 + j] - mean) * rstd * g1[j] + b1[j]);
#pragma unroll
  for (int j = 0; j < 2; j++) o2[j] = (_Float16)((v[8 + j] - mean) * rstd * g2[j] + b2[j]);
  *(half4*)(outp + lane * 4) = o0;
  *(half4*)(outp + 256 + lane * 4) = o1;
  *(half2v*)(outp + 512 + lane * 2) = o2;
}

__global__ void cvt_kernel(const float* __restrict__ s, _Float16* __restrict__ d, int n) {
  int i = blockIdx.x * blockDim.x + threadIdx.x;
  const int stride = gridDim.x * blockDim.x;
  for (; i < n; i += stride) d[i] = (_Float16)s[i];
}

__global__ void zero_kernel(float* __restrict__ p, int n) {
  const int i = blockIdx.x * blockDim.x + threadIdx.x;
  if (i < n) p[i] = 0.f;
}

__global__ void pool_kernel(const _Float16* __restrict__ h, float* __restrict__ pooled) {
  const int b = blockIdx.x, chunk = blockIdx.y;  // 32 rows per chunk
  for (int d = threadIdx.x; d < DMODEL; d += 256) {
    float s = 0.f;
    const _Float16* p = h + ((size_t)b * LSEQ + chunk * 32) * DMODEL + d;
#pragma unroll 4
    for (int l = 0; l < 32; l++) s += (float)p[(size_t)l * DMODEL];
    atomicAdd(&pooled[b * DMODEL + d], s);
  }
}

__global__ void lnvec_kernel(const float* __restrict__ pooled, const float* __restrict__ g,
                             const float* __restrict__ bta, float* __restrict__ eln) {
  const int b = blockIdx.x, lane = threadIdx.x;  // 64 threads
  float v[10], s = 0.f, ss = 0.f;
#pragma unroll
  for (int i = 0; i < 10; i++) {
    const float x = pooled[b * DMODEL + lane + 64 * i];
    v[i] = x; s += x; ss += x * x;
  }
#pragma unroll
  for (int d = 1; d < 64; d <<= 1) { s += __shfl_xor(s, d); ss += __shfl_xor(ss, d); }
  const float mean = s * (1.f / DMODEL);
  const float var = ss * (1.f / DMODEL) - mean * mean;
  const float rstd = rsqrtf(var + 1e-5f);
#pragma unroll
  for (int i = 0; i < 10; i++) {
    const int d = lane + 64 * i;
    eln[b * DMODEL + d] = (v[i] - mean) * rstd * g[d] + bta[d];
  }
}

// one wave per output element
__global__ __launch_bounds__(256) void embed_kernel(const float* __restrict__ eln,
                                                    const float* __restrict__ We,
                                                    const float* __restrict__ be,
                                                    float* __restrict__ e) {
  const int gw = (blockIdx.x << 2) + (threadIdx.x >> 6);
  const int lane = threadIdx.x & 63;
  const int b = gw / DMODEL, n = gw % DMODEL;
  const float* wr = We + (size_t)n * DMODEL;
  const float* er = eln + (size_t)b * DMODEL;
  float s = 0.f;
#pragma unroll
  for (int i = 0; i < 10; i++) s += wr[lane + 64 * i] * er[lane + 64 * i];
#pragma unroll
  for (int d = 1; d < 64; d <<= 1) s += __shfl_xor(s, d);
  if (lane == 0) e[(size_t)b * DMODEL + n] = fmaxf(s + be[n], 0.f);
}

__global__ void cosine_kernel(const float* __restrict__ ex, const float* __restrict__ ey,
                              float* __restrict__ out) {
  const int b = blockIdx.x, lane = threadIdx.x;  // 64 threads
  float sxy = 0.f, sxx = 0.f, syy = 0.f;
#pragma unroll
  for (int i = 0; i < 10; i++) {
    const float x = ex[b * DMODEL + lane + 64 * i];
    const float y = ey[b * DMODEL + lane + 64 * i];
    sxy += x * y; sxx += x * x; syy += y * y;
  }
#pragma unroll
  for (int d = 1; d < 64; d <<= 1) {
    sxy += __shfl_xor(sxy, d); sxx += __shfl_xor(sxx, d); syy += __shfl_xor(syy, d);
  }
  if (lane == 0) {
    const float nx = fmaxf(sqrtf(sxx), 1e-8f);
    const float ny = fmaxf(sqrtf(syy), 1e-8f);
    out[b] = sxy / (nx * ny);
  }
}

// ---------------------------------------------------------------------------

extern "C" void kernel_launch(void* const* d_in, const int* in_sizes, int n_in,
                              void* d_out, int out_size, void* d_ws, size_t ws_size,
                              hipStream_t stream) {
  (void)in_sizes; (void)n_in; (void)out_size;
  const float* x    = (const float*)d_in[0];
  const float* y    = (const float*)d_in[3];
  const float* Wqkv = (const float*)d_in[6];
  const float* bqkv = (const float*)d_in[7];
  const float* Wo   = (const float*)d_in[8];
  const float* bo   = (const float*)d_in[9];
  const float* ln1g = (const float*)d_in[10];
  const float* ln1b = (const float*)d_in[11];
  const float* W1   = (const float*)d_in[12];
  const float* b1   = (const float*)d_in[13];
  const float* W2   = (const float*)d_in[14];
  const float* b2   = (const float*)d_in[15];
  const float* ln2g = (const float*)d_in[16];
  const float* ln2b = (const float*)d_in[17];
  const float* lneg = (const float*)d_in[18];
  const float* lneb = (const float*)d_in[19];
  const float* We   = (const float*)d_in[20];
  const float* be   = (const float*)d_in[21];

  auto algn = [](size_t b) { return (b + 255) & ~(size_t)255; };
  const size_t wbytes = algn((size_t)NLAYER * 3 * DMODEL * DMODEL * 2) +
                        algn((size_t)NLAYER * DMODEL * DMODEL * 2) +
                        2 * algn((size_t)NLAYER * FDIM * DMODEL * 2);
  auto actbytes = [&](size_t R) {
    return algn(R * DMODEL * 2) + algn(R * 3 * DMODEL * 2) + algn(R * FDIM * 2) +
           4 * algn((size_t)BDIM * DMODEL * 4);
  };
  const int NS = (wbytes + actbytes((size_t)2 * MROWS) <= ws_size) ? 2 : 1;
  const size_t R = (size_t)NS * MROWS;

  char* ws = (char*)d_ws;
  size_t off = 0;
  auto alloc = [&](size_t bytes) -> char* {
    char* p = ws + off;
    off += algn(bytes);
    return p;
  };
  _Float16* Wqkv_h = (_Float16*)alloc((size_t)NLAYER * 3 * DMODEL * DMODEL * 2);
  _Float16* Wo_h   = (_Float16*)alloc((size_t)NLAYER * DMODEL * DMODEL * 2);
  _Float16* W1_h   = (_Float16*)alloc((size_t)NLAYER * FDIM * DMODEL * 2);
  _Float16* W2_h   = (_Float16*)alloc((size_t)NLAYER * DMODEL * FDIM * 2);
  _Float16* h_h    = (_Float16*)alloc(R * DMODEL * 2);
  _Float16* qkv_h  = (_Float16*)alloc(R * 3 * DMODEL * 2);  // aliases tmp
  _Float16* ff_h   = (_Float16*)alloc(R * FDIM * 2);        // aliases o_h
  float*    pooled = (float*)   alloc((size_t)BDIM * DMODEL * 4);
  float*    elnb   = (float*)   alloc((size_t)BDIM * DMODEL * 4);
  float*    exb    = (float*)   alloc((size_t)BDIM * DMODEL * 4);
  float*    eyb    = (float*)   alloc((size_t)BDIM * DMODEL * 4);
  if (off > ws_size) return;
  _Float16* tmp  = qkv_h;    // pre-LN sums; qkv dead once attn has run
  _Float16* o_h  = ff_h;     // o dead before ff is written

  cvt_kernel<<<2048, 256, 0, stream>>>(Wqkv, Wqkv_h, NLAYER * 3 * DMODEL * DMODEL);
  cvt_kernel<<<2048, 256, 0, stream>>>(Wo,   Wo_h,   NLAYER * DMODEL * DMODEL);
  cvt_kernel<<<2048, 256, 0, stream>>>(W1,   W1_h,   NLAYER * FDIM * DMODEL);
  cvt_kernel<<<2048, 256, 0, stream>>>(W2,   W2_h,   NLAYER * DMODEL * FDIM);

  const float* seq_in[2] = {x, y};
  float* eouts[2] = {exb, eyb};
  const int Mr = (int)R;

  for (int s0 = 0; s0 < 2; s0 += NS) {
    for (int s = 0; s < NS; s++)
      cvt_kernel<<<2048, 256, 0, stream>>>(
          seq_in[s0 + s], h_h + (size_t)s * MROWS * DMODEL, MROWS * DMODEL);
    for (int l = 0; l < NLAYER; l++) {
      // qkv = h @ Wqkv^T + bqkv
      gemm_bt<false, false, 2><<<dim3(Mr / 128, 15), 256, 0, stream>>>(
          h_h, Wqkv_h + (size_t)l * 3 * DMODEL * DMODEL, bqkv + l * 3 * DMODEL,
          nullptr, qkv_h, Mr, 3 * DMODEL, DMODEL, DMODEL);
      attn_kernel<<<dim3(LSEQ / 64, NHEAD, Mr / LSEQ), 256, 0, stream>>>(qkv_h, o_h);
      // tmp = o @ Wo^T + bo + h   (full K, residual inline)
      gemm_bt<false, true, 1><<<dim3(Mr / 128, 5), 256, 0, stream>>>(
          o_h, Wo_h + (size_t)l * DMODEL * DMODEL, bo + l * DMODEL,
          h_h, tmp, Mr, DMODEL, DMODEL, DMODEL);
      ln_res1_kernel<<<Mr / 4, 256, 0, stream>>>(
          tmp, ln1g + l * DMODEL, ln1b + l * DMODEL, h_h);
      // ff = relu(h @ W1^T + b1)
      gemm_bt<true, false, 1><<<dim3(Mr / 128, 10), 256, 0, stream>>>(
          h_h, W1_h + (size_t)l * FDIM * DMODEL, b1 + l * FDIM,
          nullptr, ff_h, Mr, FDIM, DMODEL, DMODEL);
      // tmp = ff @ W2^T + b2 + h  (full K=1280, residual inline)
      gemm_bt<false, true, 1><<<dim3(Mr / 128, 5), 256, 0, stream>>>(
          ff_h, W2_h + (size_t)l * DMODEL * FDIM, b2 + l * DMODEL,
          h_h, tmp, Mr, DMODEL, FDIM, FDIM);
      ln_res1_kernel<<<Mr / 4, 256, 0, stream>>>(
          tmp, ln2g + l * DMODEL, ln2b + l * DMODEL, h_h);
    }
    for (int s = 0; s < NS; s++) {
      const _Float16* hseq = h_h + (size_t)s * MROWS * DMODEL;
      zero_kernel<<<(BDIM * DMODEL + 255) / 256, 256, 0, stream>>>(pooled, BDIM * DMODEL);
      pool_kernel<<<dim3(BDIM, 32), 256, 0, stream>>>(hseq, pooled);
      lnvec_kernel<<<BDIM, 64, 0, stream>>>(pooled, lneg, lneb, elnb);
      embed_kernel<<<BDIM * DMODEL / 4, 256, 0, stream>>>(elnb, We, be, eouts[s0 + s]);
    }
  }
  cosine_kernel<<<BDIM, 64, 0, stream>>>(exb, eyb, (float*)d_out);
}

// Round 13
// 1580.174 us; speedup vs baseline: 2.1289x; 2.1257x over previous
//
#include <hip/hip_runtime.h>

// ---------------------------------------------------------------------------
// MaskedTransformerEmbeddingCosine on MI355X (gfx950)
// R19: grid-tail test with ONLY measured-good kernel bodies. The templated
//      SUBS=1 rewrite (R17/R18) scratch-spilled regardless of launch_bounds
//      (WRITE 164MB vs 21MB real, 149 µs) — array-staging formulation, not
//      occupancy, was the defect. This round: gemm_bt32 = byte-for-byte copy
//      of the VERIFIED R6 BK=32 body (named scalars, 32 KB LDS, VGPR 76,
//      WRITE exact) + RESADD/RELU epilogue, used for Wo/W1/W2 (640/1280-block
//      grids). QKV keeps the verified non-templated BK=64 body. attn keeps
//      R13+R16; R12 de-split-K retained.
// ---------------------------------------------------------------------------

#define LSEQ   1024
#define DMODEL 640
#define NHEAD  10
#define DHEAD  64
#define NLAYER 6
#define BDIM   8
#define FDIM   1280
#define MROWS  (BDIM * LSEQ)

typedef __attribute__((ext_vector_type(8))) _Float16 half8;
typedef __attribute__((ext_vector_type(4))) _Float16 half4;
typedef __attribute__((ext_vector_type(2))) _Float16 half2v;
typedef __attribute__((ext_vector_type(4))) float    floatx4;
typedef __attribute__((ext_vector_type(2))) float    floatx2;

// ---------------------------------------------------------------------------
// C = A(M,:) @ B(N,:)^T + bias [+ res] [relu]; BK=64 (2 BK=32 subs), 64 KB
// LDS. Verified R8/R16 body (named scalars). Used for QKV (1920-block grid).
// ---------------------------------------------------------------------------
template <bool RELU, bool RESADD>
__global__ __launch_bounds__(256) void gemm_bt(const _Float16* __restrict__ A,
                                               const _Float16* __restrict__ Bw,
                                               const float* __restrict__ bias,
                                               const _Float16* __restrict__ res,
                                               _Float16* __restrict__ Cout,
                                               int M, int N, int K, int ld) {
  __shared__ _Float16 As[2][2][128 * 32];
  __shared__ _Float16 Bs[2][2][128 * 32];
  const int m0 = blockIdx.x * 128, n0 = blockIdx.y * 128;
  const int tid = threadIdx.x;
  const int w = tid >> 6, lane = tid & 63;
  const int quad = lane >> 4, l16 = lane & 15;
  const int wm = w >> 1, wn = w & 1;

  floatx4 acc[4][4];
#pragma unroll
  for (int i = 0; i < 4; i++)
#pragma unroll
    for (int j = 0; j < 4; j++) acc[i][j] = (floatx4){0.f, 0.f, 0.f, 0.f};

  const int arow = w * 16 + (lane >> 2);
  const int kswz = ((lane & 3) ^ ((lane >> 3) & 3)) * 8;
  const _Float16* ag = A + (size_t)(m0 + arow) * ld + kswz;
  const _Float16* bg = Bw + (size_t)(n0 + arow) * ld + kswz;
  const size_t r64 = (size_t)64 * ld;
  const int wofs0 = arow * 32 + (lane & 3) * 8;
  const int wofs1 = wofs0 + 64 * 32;

  const int fro = l16 * 32 + ((quad ^ ((l16 >> 1) & 3)) * 8);

  const int nIter = K >> 6;
  {
    uint4 a00 = *(const uint4*)ag;
    uint4 a01 = *(const uint4*)(ag + r64);
    uint4 a10 = *(const uint4*)(ag + 32);
    uint4 a11 = *(const uint4*)(ag + 32 + r64);
    uint4 b00 = *(const uint4*)bg;
    uint4 b01 = *(const uint4*)(bg + r64);
    uint4 b10 = *(const uint4*)(bg + 32);
    uint4 b11 = *(const uint4*)(bg + 32 + r64);
    ag += 64; bg += 64;
    *(uint4*)&As[0][0][wofs0] = a00;
    *(uint4*)&As[0][0][wofs1] = a01;
    *(uint4*)&As[0][1][wofs0] = a10;
    *(uint4*)&As[0][1][wofs1] = a11;
    *(uint4*)&Bs[0][0][wofs0] = b00;
    *(uint4*)&Bs[0][0][wofs1] = b01;
    *(uint4*)&Bs[0][1][wofs0] = b10;
    *(uint4*)&Bs[0][1][wofs1] = b11;
  }

  for (int i = 0; i < nIter; i++) {
    __syncthreads();
    uint4 a00, a01, a10, a11, b00, b01, b10, b11;
    const bool pf = (i + 1 < nIter);
    if (pf) {
      a00 = *(const uint4*)ag;
      a01 = *(const uint4*)(ag + r64);
      a10 = *(const uint4*)(ag + 32);
      a11 = *(const uint4*)(ag + 32 + r64);
      b00 = *(const uint4*)bg;
      b01 = *(const uint4*)(bg + r64);
      b10 = *(const uint4*)(bg + 32);
      b11 = *(const uint4*)(bg + 32 + r64);
      ag += 64; bg += 64;
    }
#pragma unroll
    for (int sub = 0; sub < 2; sub++) {
      const _Float16* as = As[i & 1][sub];
      const _Float16* bs = Bs[i & 1][sub];
      half8 af[4], bf[4];
#pragma unroll
      for (int mt = 0; mt < 4; mt++)
        af[mt] = *(const half8*)&as[(wm * 64 + mt * 16) * 32 + fro];
#pragma unroll
      for (int nt = 0; nt < 4; nt++)
        bf[nt] = *(const half8*)&bs[(wn * 64 + nt * 16) * 32 + fro];
#pragma unroll
      for (int mt = 0; mt < 4; mt++)
#pragma unroll
        for (int nt = 0; nt < 4; nt++)
          acc[mt][nt] = __builtin_amdgcn_mfma_f32_16x16x32_f16(af[mt], bf[nt], acc[mt][nt], 0, 0, 0);
    }
    if (pf) {
      const int nb = (i + 1) & 1;
      *(uint4*)&As[nb][0][wofs0] = a00;
      *(uint4*)&As[nb][0][wofs1] = a01;
      *(uint4*)&As[nb][1][wofs0] = a10;
      *(uint4*)&As[nb][1][wofs1] = a11;
      *(uint4*)&Bs[nb][0][wofs0] = b00;
      *(uint4*)&Bs[nb][0][wofs1] = b01;
      *(uint4*)&Bs[nb][1][wofs0] = b10;
      *(uint4*)&Bs[nb][1][wofs1] = b11;
    }
  }

  float bv[4];
#pragma unroll
  for (int nt = 0; nt < 4; nt++)
    bv[nt] = bias[n0 + wn * 64 + nt * 16 + l16];
#pragma unroll
  for (int mt = 0; mt < 4; mt++) {
#pragma unroll
    for (int reg = 0; reg < 4; reg++) {
      const int row = m0 + wm * 64 + mt * 16 + quad * 4 + reg;
#pragma unroll
      for (int nt = 0; nt < 4; nt++) {
        const int col = n0 + wn * 64 + nt * 16 + l16;
        float v = acc[mt][nt][reg] + bv[nt];
        if (RESADD) v += (float)res[(size_t)row * N + col];
        if (RELU) v = fmaxf(v, 0.f);
        Cout[(size_t)row * N + col] = (_Float16)v;
      }
    }
  }
}

// ---------------------------------------------------------------------------
// Same contract, BK=32, 32 KB LDS — byte-for-byte the verified R6 loop body
// (named scalars; measured 67 µs / VGPR 76 / exact WRITE_SIZE at K=640).
// Used for Wo/W1/W2 (640/1280-block grids) to cut the partial-round tail.
// ---------------------------------------------------------------------------
template <bool RELU, bool RESADD>
__global__ __launch_bounds__(256) void gemm_bt32(const _Float16* __restrict__ A,
                                                 const _Float16* __restrict__ Bw,
                                                 const float* __restrict__ bias,
                                                 const _Float16* __restrict__ res,
                                                 _Float16* __restrict__ Cout,
                                                 int M, int N, int K, int ld) {
  __shared__ _Float16 As[2][128 * 32];
  __shared__ _Float16 Bs[2][128 * 32];
  const int m0 = blockIdx.x * 128, n0 = blockIdx.y * 128;
  const int tid = threadIdx.x;
  const int w = tid >> 6, lane = tid & 63;
  const int quad = lane >> 4, l16 = lane & 15;
  const int wm = w >> 1, wn = w & 1;

  floatx4 acc[4][4];
#pragma unroll
  for (int i = 0; i < 4; i++)
#pragma unroll
    for (int j = 0; j < 4; j++) acc[i][j] = (floatx4){0.f, 0.f, 0.f, 0.f};

  const int arow = w * 16 + (lane >> 2);
  const int kswz = ((lane & 3) ^ ((lane >> 3) & 3)) * 8;
  const _Float16* ag = A + (size_t)(m0 + arow) * ld + kswz;
  const _Float16* bg = Bw + (size_t)(n0 + arow) * ld + kswz;
  const size_t krows = (size_t)64 * ld;
  const int wofs0 = arow * 32 + (lane & 3) * 8;
  const int wofs1 = wofs0 + 64 * 32;

  const int fro = l16 * 32 + ((quad ^ ((l16 >> 1) & 3)) * 8);

  const int nIter = K >> 5;
  {
    uint4 a0 = *(const uint4*)ag;
    uint4 a1 = *(const uint4*)(ag + krows);
    uint4 b0 = *(const uint4*)bg;
    uint4 b1 = *(const uint4*)(bg + krows);
    ag += 32; bg += 32;
    *(uint4*)&As[0][wofs0] = a0;
    *(uint4*)&As[0][wofs1] = a1;
    *(uint4*)&Bs[0][wofs0] = b0;
    *(uint4*)&Bs[0][wofs1] = b1;
  }

  for (int i = 0; i < nIter; i++) {
    __syncthreads();
    uint4 na0, na1, nb0, nb1;
    const bool pf = (i + 1 < nIter);
    if (pf) {
      na0 = *(const uint4*)ag;
      na1 = *(const uint4*)(ag + krows);
      nb0 = *(const uint4*)bg;
      nb1 = *(const uint4*)(bg + krows);
      ag += 32; bg += 32;
    }
    const _Float16* as = As[i & 1];
    const _Float16* bs = Bs[i & 1];
    half8 af[4], bf[4];
#pragma unroll
    for (int mt = 0; mt < 4; mt++)
      af[mt] = *(const half8*)&as[(wm * 64 + mt * 16) * 32 + fro];
#pragma unroll
    for (int nt = 0; nt < 4; nt++)
      bf[nt] = *(const half8*)&bs[(wn * 64 + nt * 16) * 32 + fro];
#pragma unroll
    for (int mt = 0; mt < 4; mt++)
#pragma unroll
      for (int nt = 0; nt < 4; nt++)
        acc[mt][nt] = __builtin_amdgcn_mfma_f32_16x16x32_f16(af[mt], bf[nt], acc[mt][nt], 0, 0, 0);
    if (pf) {
      _Float16* asn = As[(i + 1) & 1];
      _Float16* bsn = Bs[(i + 1) & 1];
      *(uint4*)&asn[wofs0] = na0;
      *(uint4*)&asn[wofs1] = na1;
      *(uint4*)&bsn[wofs0] = nb0;
      *(uint4*)&bsn[wofs1] = nb1;
    }
  }

  float bv[4];
#pragma unroll
  for (int nt = 0; nt < 4; nt++)
    bv[nt] = bias[n0 + wn * 64 + nt * 16 + l16];
#pragma unroll
  for (int mt = 0; mt < 4; mt++) {
#pragma unroll
    for (int reg = 0; reg < 4; reg++) {
      const int row = m0 + wm * 64 + mt * 16 + quad * 4 + reg;
#pragma unroll
      for (int nt = 0; nt < 4; nt++) {
        const int col = n0 + wn * 64 + nt * 16 + l16;
        float v = acc[mt][nt][reg] + bv[nt];
        if (RESADD) v += (float)res[(size_t)row * N + col];
        if (RELU) v = fmaxf(v, 0.f);
        Cout[(size_t)row * N + col] = (_Float16)v;
      }
    }
  }
}

// ---------------------------------------------------------------------------
// Banded attention: one block per (64-query tile, head, row-batch of 1024).
// T14 async-STAGE: V global loads issue in phase 0 (held in regs); the
// V->Vt LDS scatter runs AFTER QK^T. Q in regs (R13); Vt key-chunk XOR
// swizzle (R9). 3 barriers; LDS 53.2 KB -> 3 blocks/CU.
// ---------------------------------------------------------------------------
__global__ __launch_bounds__(256) void attn_kernel(const _Float16* __restrict__ qkv,
                                                   _Float16* __restrict__ o) {
  __shared__ _Float16 KP[192 * 72];   // K tiles; later reused as P (64 x 200)
  __shared__ _Float16 Vt[64 * 200];   // V transposed (key-swizzled)
  const int qb = blockIdx.x, h = blockIdx.y, b = blockIdx.z;
  const int q0 = qb * 64;
  const int kc0 = (q0 - 64 > 0) ? q0 - 64 : 0;
  const int kend = (q0 + 128 < LSEQ) ? q0 + 128 : LSEQ;
  const int cnt = kend - kc0;
  const int tid = threadIdx.x;
  const int w = tid >> 6, lane = tid & 63, quad = lane >> 4, l16 = lane & 15;

  // ---- phase 0: issue V loads into regs; stage K; load Q frags ----
  uint4 vreg[6];
#pragma unroll
  for (int it = 0; it < 6; it++) {
    const int c = tid + it * 256;
    const int row = c >> 3, ch = c & 7;
    uint4 v = {0u, 0u, 0u, 0u};
    if (row < cnt)
      v = *(const uint4*)(qkv + (size_t)(b * LSEQ + kc0 + row) * (3 * DMODEL) + 2 * DMODEL + h * DHEAD + ch * 8);
    vreg[it] = v;
  }
  half8 qf[2];
#pragma unroll
  for (int ks = 0; ks < 2; ks++)
    qf[ks] = *(const half8*)(qkv + (size_t)(b * LSEQ + q0 + w * 16 + l16) * (3 * DMODEL) +
                             h * DHEAD + ks * 32 + quad * 8);
#pragma unroll
  for (int it = 0; it < 6; it++) {
    const int c = tid + it * 256;
    const int row = c >> 3, ch = c & 7;
    uint4 v = {0u, 0u, 0u, 0u};
    if (row < cnt)
      v = *(const uint4*)(qkv + (size_t)(b * LSEQ + kc0 + row) * (3 * DMODEL) + DMODEL + h * DHEAD + ch * 8);
    *(uint4*)&KP[row * 72 + ch * 8] = v;
  }
  __syncthreads();  // (A) K staged; V loads still in flight

  // ---- QK^T (V latency hides under these MFMAs) ----
  floatx4 sacc[12];
#pragma unroll
  for (int i = 0; i < 12; i++) sacc[i] = (floatx4){0.f, 0.f, 0.f, 0.f};
#pragma unroll
  for (int ks = 0; ks < 2; ks++) {
#pragma unroll
    for (int nt = 0; nt < 12; nt++) {
      const half8 kf = *(const half8*)&KP[(nt * 16 + l16) * 72 + ks * 32 + quad * 8];
      sacc[nt] = __builtin_amdgcn_mfma_f32_16x16x32_f16(qf[ks], kf, sacc[nt], 0, 0, 0);
    }
  }

  // ---- write Vt from regs (disjoint from KP; lands before barrier C) ----
#pragma unroll
  for (int it = 0; it < 6; it++) {
    const int c = tid + it * 256;
    const int row = c >> 3, ch = c & 7;
    _Float16 tmp[8];
    *(uint4*)tmp = vreg[it];
    const int rs = row ^ (ch << 3);  // key-swizzle by d>>3 (= ch), bijective in [0,192)
#pragma unroll
    for (int jj = 0; jj < 8; jj++) Vt[(ch * 8 + jj) * 200 + rs] = tmp[jj];
  }
  __syncthreads();  // (B) all K reads done; Vt writes done

  // ---- softmax; P overwrites K region of KP ----
#pragma unroll
  for (int r = 0; r < 4; r++) {
    const int qi = q0 + w * 16 + quad * 4 + r;
    float sv[12];
    float m = -1e30f;
#pragma unroll
    for (int nt = 0; nt < 12; nt++) {
      const int key = kc0 + nt * 16 + l16;
      const bool ok = (key >= qi - 64) && (key <= qi + 64) && (key < LSEQ);
      const float s = ok ? sacc[nt][r] * 0.125f : -1e30f;
      sv[nt] = s;
      m = fmaxf(m, s);
    }
#pragma unroll
    for (int d = 1; d < 16; d <<= 1) m = fmaxf(m, __shfl_xor(m, d));
    float sum = 0.f;
#pragma unroll
    for (int nt = 0; nt < 12; nt++) {
      const float p = __expf(sv[nt] - m);
      sv[nt] = p;
      sum += p;
    }
#pragma unroll
    for (int d = 1; d < 16; d <<= 1) sum += __shfl_xor(sum, d);
    const float inv = 1.f / sum;
    _Float16* Pr = &KP[(w * 16 + quad * 4 + r) * 200];
#pragma unroll
    for (int nt = 0; nt < 12; nt++) Pr[nt * 16 + l16] = (_Float16)(sv[nt] * inv);
  }
  __syncthreads();  // (C)

  // ---- PV ----
  floatx4 oacc[4];
#pragma unroll
  for (int i = 0; i < 4; i++) oacc[i] = (floatx4){0.f, 0.f, 0.f, 0.f};
#pragma unroll
  for (int ks = 0; ks < 6; ks++) {
    const half8 pf = *(const half8*)&KP[(w * 16 + l16) * 200 + ks * 32 + quad * 8];
#pragma unroll
    for (int nt = 0; nt < 4; nt++) {
      const int dsw = ((nt * 2 + (l16 >> 3)) & 7) << 3;  // (d>>3)&7 of this lane's V row
      const half8 vf = *(const half8*)&Vt[(nt * 16 + l16) * 200 + ((ks * 32 + quad * 8) ^ dsw)];
      oacc[nt] = __builtin_amdgcn_mfma_f32_16x16x32_f16(pf, vf, oacc[nt], 0, 0, 0);
    }
  }
#pragma unroll
  for (int nt = 0; nt < 4; nt++)
#pragma unroll
    for (int reg = 0; reg < 4; reg++) {
      const int row = q0 + w * 16 + quad * 4 + reg;
      const int col = h * DHEAD + nt * 16 + l16;
      o[(size_t)(b * LSEQ + row) * DMODEL + col] = (_Float16)oacc[nt][reg];
    }
}

// ---------------------------------------------------------------------------
// h = LayerNorm(s) — fp16 in (bias+residual already applied), fp16 out.
// One wave/row, vectorized 640 = 64*4 + 64*4 + 64*2.
// ---------------------------------------------------------------------------
__global__ __launch_bounds__(256) void ln_res1_kernel(const _Float16* __restrict__ s0,
                                                      const float* __restrict__ g,
                                                      const float* __restrict__ bta,
                                                      _Float16* __restrict__ hh) {
  const int row = blockIdx.x * 4 + (threadIdx.x >> 6);
  const int lane = threadIdx.x & 63;
  const _Float16* p0 = s0 + (size_t)row * DMODEL;
  const half4  a0 = *(const half4*)(p0 + lane * 4);
  const half4  a1 = *(const half4*)(p0 + 256 + lane * 4);
  const half2v a2 = *(const half2v*)(p0 + 512 + lane * 2);
  float v[10], s = 0.f, ss = 0.f;
#pragma unroll
  for (int j = 0; j < 4; j++) v[j] = (float)a0[j];
#pragma unroll
  for (int j = 0; j < 4; j++) v[4 + j] = (float)a1[j];
#pragma unroll
  for (int j = 0; j < 2; j++) v[8 + j] = (float)a2[j];
#pragma unroll
  for (int i = 0; i < 10; i++) { s += v[i]; ss += v[i] * v[i]; }
#pragma unroll
  for (int d = 1; d < 64; d <<= 1) { s += __shfl_xor(s, d); ss += __shfl_xor(ss, d); }
  const float mean = s * (1.f / DMODEL);
  const float var = ss * (1.f / DMODEL) - mean * mean;
  const float rstd = rsqrtf(var + 1e-5f);
  const floatx4 g0 = *(const floatx4*)(g + lane * 4);
  const floatx4 g1 = *(const floatx4*)(g + 256 + lane * 4);
  const floatx2 g2 = *(const floatx2*)(g + 512 + lane * 2);
  const floatx4 b0 = *(const floatx4*)(bta + lane * 4);
  const floatx4 b1 = *(const floatx4*)(bta + 256 + lane * 4);
  const floatx2 b2 = *(const floatx2*)(bta + 512 + lane * 2);
  _Float16* outp = hh + (size_t)row * DMODEL;
  half4 o0, o1;
  half2v o2;
#pragma unroll
  for (int j = 0; j < 4; j++) o0[j] = (_Float16)((v[j] - mean) * rstd * g0[j] + b0[j]);
#pragma unroll
  for (int j = 0; j < 4; j++) o1[j] = (_Float16)((v[4 + j] - mean) * rstd * g1[j] + b1[j]);
#pragma unroll
  for (int j = 0; j < 2; j++) o2[j] = (_Float16)((v[8 + j] - mean) * rstd * g2[j] + b2[j]);
  *(half4*)(outp + lane * 4) = o0;
  *(half4*)(outp + 256 + lane * 4) = o1;
  *(half2v*)(outp + 512 + lane * 2) = o2;
}

__global__ void cvt_kernel(const float* __restrict__ s, _Float16* __restrict__ d, int n) {
  int i = blockIdx.x * blockDim.x + threadIdx.x;
  const int stride = gridDim.x * blockDim.x;
  for (; i < n; i += stride) d[i] = (_Float16)s[i];
}

__global__ void zero_kernel(float* __restrict__ p, int n) {
  const int i = blockIdx.x * blockDim.x + threadIdx.x;
  if (i < n) p[i] = 0.f;
}

__global__ void pool_kernel(const _Float16* __restrict__ h, float* __restrict__ pooled) {
  const int b = blockIdx.x, chunk = blockIdx.y;  // 32 rows per chunk
  for (int d = threadIdx.x; d < DMODEL; d += 256) {
    float s = 0.f;
    const _Float16* p = h + ((size_t)b * LSEQ + chunk * 32) * DMODEL + d;
#pragma unroll 4
    for (int l = 0; l < 32; l++) s += (float)p[(size_t)l * DMODEL];
    atomicAdd(&pooled[b * DMODEL + d], s);
  }
}

__global__ void lnvec_kernel(const float* __restrict__ pooled, const float* __restrict__ g,
                             const float* __restrict__ bta, float* __restrict__ eln) {
  const int b = blockIdx.x, lane = threadIdx.x;  // 64 threads
  float v[10], s = 0.f, ss = 0.f;
#pragma unroll
  for (int i = 0; i < 10; i++) {
    const float x = pooled[b * DMODEL + lane + 64 * i];
    v[i] = x; s += x; ss += x * x;
  }
#pragma unroll
  for (int d = 1; d < 64; d <<= 1) { s += __shfl_xor(s, d); ss += __shfl_xor(ss, d); }
  const float mean = s * (1.f / DMODEL);
  const float var = ss * (1.f / DMODEL) - mean * mean;
  const float rstd = rsqrtf(var + 1e-5f);
#pragma unroll
  for (int i = 0; i < 10; i++) {
    const int d = lane + 64 * i;
    eln[b * DMODEL + d] = (v[i] - mean) * rstd * g[d] + bta[d];
  }
}

// one wave per output element
__global__ __launch_bounds__(256) void embed_kernel(const float* __restrict__ eln,
                                                    const float* __restrict__ We,
                                                    const float* __restrict__ be,
                                                    float* __restrict__ e) {
  const int gw = (blockIdx.x << 2) + (threadIdx.x >> 6);
  const int lane = threadIdx.x & 63;
  const int b = gw / DMODEL, n = gw % DMODEL;
  const float* wr = We + (size_t)n * DMODEL;
  const float* er = eln + (size_t)b * DMODEL;
  float s = 0.f;
#pragma unroll
  for (int i = 0; i < 10; i++) s += wr[lane + 64 * i] * er[lane + 64 * i];
#pragma unroll
  for (int d = 1; d < 64; d <<= 1) s += __shfl_xor(s, d);
  if (lane == 0) e[(size_t)b * DMODEL + n] = fmaxf(s + be[n], 0.f);
}

__global__ void cosine_kernel(const float* __restrict__ ex, const float* __restrict__ ey,
                              float* __restrict__ out) {
  const int b = blockIdx.x, lane = threadIdx.x;  // 64 threads
  float sxy = 0.f, sxx = 0.f, syy = 0.f;
#pragma unroll
  for (int i = 0; i < 10; i++) {
    const float x = ex[b * DMODEL + lane + 64 * i];
    const float y = ey[b * DMODEL + lane + 64 * i];
    sxy += x * y; sxx += x * x; syy += y * y;
  }
#pragma unroll
  for (int d = 1; d < 64; d <<= 1) {
    sxy += __shfl_xor(sxy, d); sxx += __shfl_xor(sxx, d); syy += __shfl_xor(syy, d);
  }
  if (lane == 0) {
    const float nx = fmaxf(sqrtf(sxx), 1e-8f);
    const float ny = fmaxf(sqrtf(syy), 1e-8f);
    out[b] = sxy / (nx * ny);
  }
}

// ---------------------------------------------------------------------------

extern "C" void kernel_launch(void* const* d_in, const int* in_sizes, int n_in,
                              void* d_out, int out_size, void* d_ws, size_t ws_size,
                              hipStream_t stream) {
  (void)in_sizes; (void)n_in; (void)out_size;
  const float* x    = (const float*)d_in[0];
  const float* y    = (const float*)d_in[3];
  const float* Wqkv = (const float*)d_in[6];
  const float* bqkv = (const float*)d_in[7];
  const float* Wo   = (const float*)d_in[8];
  const float* bo   = (const float*)d_in[9];
  const float* ln1g = (const float*)d_in[10];
  const float* ln1b = (const float*)d_in[11];
  const float* W1   = (const float*)d_in[12];
  const float* b1   = (const float*)d_in[13];
  const float* W2   = (const float*)d_in[14];
  const float* b2   = (const float*)d_in[15];
  const float* ln2g = (const float*)d_in[16];
  const float* ln2b = (const float*)d_in[17];
  const float* lneg = (const float*)d_in[18];
  const float* lneb = (const float*)d_in[19];
  const float* We   = (const float*)d_in[20];
  const float* be   = (const float*)d_in[21];

  auto algn = [](size_t b) { return (b + 255) & ~(size_t)255; };
  const size_t wbytes = algn((size_t)NLAYER * 3 * DMODEL * DMODEL * 2) +
                        algn((size_t)NLAYER * DMODEL * DMODEL * 2) +
                        2 * algn((size_t)NLAYER * FDIM * DMODEL * 2);
  auto actbytes = [&](size_t R) {
    return algn(R * DMODEL * 2) + algn(R * 3 * DMODEL * 2) + algn(R * FDIM * 2) +
           4 * algn((size_t)BDIM * DMODEL * 4);
  };
  const int NS = (wbytes + actbytes((size_t)2 * MROWS) <= ws_size) ? 2 : 1;
  const size_t R = (size_t)NS * MROWS;

  char* ws = (char*)d_ws;
  size_t off = 0;
  auto alloc = [&](size_t bytes) -> char* {
    char* p = ws + off;
    off += algn(bytes);
    return p;
  };
  _Float16* Wqkv_h = (_Float16*)alloc((size_t)NLAYER * 3 * DMODEL * DMODEL * 2);
  _Float16* Wo_h   = (_Float16*)alloc((size_t)NLAYER * DMODEL * DMODEL * 2);
  _Float16* W1_h   = (_Float16*)alloc((size_t)NLAYER * FDIM * DMODEL * 2);
  _Float16* W2_h   = (_Float16*)alloc((size_t)NLAYER * DMODEL * FDIM * 2);
  _Float16* h_h    = (_Float16*)alloc(R * DMODEL * 2);
  _Float16* qkv_h  = (_Float16*)alloc(R * 3 * DMODEL * 2);  // aliases tmp
  _Float16* ff_h   = (_Float16*)alloc(R * FDIM * 2);        // aliases o_h
  float*    pooled = (float*)   alloc((size_t)BDIM * DMODEL * 4);
  float*    elnb   = (float*)   alloc((size_t)BDIM * DMODEL * 4);
  float*    exb    = (float*)   alloc((size_t)BDIM * DMODEL * 4);
  float*    eyb    = (float*)   alloc((size_t)BDIM * DMODEL * 4);
  if (off > ws_size) return;
  _Float16* tmp  = qkv_h;    // pre-LN sums; qkv dead once attn has run
  _Float16* o_h  = ff_h;     // o dead before ff is written

  cvt_kernel<<<2048, 256, 0, stream>>>(Wqkv, Wqkv_h, NLAYER * 3 * DMODEL * DMODEL);
  cvt_kernel<<<2048, 256, 0, stream>>>(Wo,   Wo_h,   NLAYER * DMODEL * DMODEL);
  cvt_kernel<<<2048, 256, 0, stream>>>(W1,   W1_h,   NLAYER * FDIM * DMODEL);
  cvt_kernel<<<2048, 256, 0, stream>>>(W2,   W2_h,   NLAYER * DMODEL * FDIM);

  const float* seq_in[2] = {x, y};
  float* eouts[2] = {exb, eyb};
  const int Mr = (int)R;

  for (int s0 = 0; s0 < 2; s0 += NS) {
    for (int s = 0; s < NS; s++)
      cvt_kernel<<<2048, 256, 0, stream>>>(
          seq_in[s0 + s], h_h + (size_t)s * MROWS * DMODEL, MROWS * DMODEL);
    for (int l = 0; l < NLAYER; l++) {
      // qkv = h @ Wqkv^T + bqkv
      gemm_bt<false, false><<<dim3(Mr / 128, 15), 256, 0, stream>>>(
          h_h, Wqkv_h + (size_t)l * 3 * DMODEL * DMODEL, bqkv + l * 3 * DMODEL,
          nullptr, qkv_h, Mr, 3 * DMODEL, DMODEL, DMODEL);
      attn_kernel<<<dim3(LSEQ / 64, NHEAD, Mr / LSEQ), 256, 0, stream>>>(qkv_h, o_h);
      // tmp = o @ Wo^T + bo + h   (full K, residual inline)
      gemm_bt32<false, true><<<dim3(Mr / 128, 5), 256, 0, stream>>>(
          o_h, Wo_h + (size_t)l * DMODEL * DMODEL, bo + l * DMODEL,
          h_h, tmp, Mr, DMODEL, DMODEL, DMODEL);
      ln_res1_kernel<<<Mr / 4, 256, 0, stream>>>(
          tmp, ln1g + l * DMODEL, ln1b + l * DMODEL, h_h);
      // ff = relu(h @ W1^T + b1)
      gemm_bt32<true, false><<<dim3(Mr / 128, 10), 256, 0, stream>>>(
          h_h, W1_h + (size_t)l * FDIM * DMODEL, b1 + l * FDIM,
          nullptr, ff_h, Mr, FDIM, DMODEL, DMODEL);
      // tmp = ff @ W2^T + b2 + h  (full K=1280, residual inline)
      gemm_bt32<false, true><<<dim3(Mr / 128, 5), 256, 0, stream>>>(
          ff_h, W2_h + (size_t)l * DMODEL * FDIM, b2 + l * DMODEL,
          h_h, tmp, Mr, DMODEL, FDIM, FDIM);
      ln_res1_kernel<<<Mr / 4, 256, 0, stream>>>(
          tmp, ln2g + l * DMODEL, ln2b + l * DMODEL, h_h);
    }
    for (int s = 0; s < NS; s++) {
      const _Float16* hseq = h_h + (size_t)s * MROWS * DMODEL;
      zero_kernel<<<(BDIM * DMODEL + 255) / 256, 256, 0, stream>>>(pooled, BDIM * DMODEL);
      pool_kernel<<<dim3(BDIM, 32), 256, 0, stream>>>(hseq, pooled);
      lnvec_kernel<<<BDIM, 64, 0, stream>>>(pooled, lneg, lneb, elnb);
      embed_kernel<<<BDIM * DMODEL / 4, 256, 0, stream>>>(elnb, We, be, eouts[s0 + s]);
    }
  }
  cosine_kernel<<<BDIM, 64, 0, stream>>>(exb, eyb, (float*)d_out);
}